// Round 5
// baseline (144.363 us; speedup 1.0000x reference)
//
#include <hip/hip_runtime.h>

namespace {

typedef float v2f __attribute__((ext_vector_type(2)));

constexpr int kB = 4, kCin = 4, kCout = 4;
constexpr int kD1 = 32, kD2 = 32, kH = 64, kW = 64;
constexpr int kHO = 32, kWO = 32;
constexpr int kSlice = kH * kW;                       // 4096
constexpr size_t kCiStride = (size_t)kD1 * kD2 * kSlice;

__global__ __launch_bounds__(256)
void conv4d_strang(const float* __restrict__ x, const float* __restrict__ w,
                   const float* __restrict__ bias, float* __restrict__ y)
{
    // ---- XCD-chunked decode: chunk=(b, h-half) -> one XCD owns 32MB of x.
    // Round-robin HW mapping: XCD = blockIdx % 8. Within a chunk: tv fastest,
    // then tu, then h-subtile, keeping the (u,v) halo slices L2-resident.
    const unsigned orig  = blockIdx.x;       // 0..4095
    const unsigned chunk = orig & 7;         // XCD id
    const unsigned rem   = orig >> 3;        // 0..511
    const int b     = chunk >> 1;            // 0..3
    const int hhalf = chunk & 1;             // 0..1
    const int htsub = rem >> 8;              // 0..1
    const int tu    = (rem >> 4) & 15;       // 0..15
    const int tv    = rem & 15;              // 0..15
    const int u0 = 2 * tu, v0 = 2 * tv;      // 2x2 (u,v) register tile
    const int ho0 = (hhalf * 2 + htsub) * 8;

    const int wo = threadIdx.x;              // 0..31 -> one output column
    const int hy = threadIdx.y;              // 0..7
    const int ho = ho0 + hy;
    const int toff = (2 * ho) * kW + 2 * wo; // per-thread elem offset in a slice

    // acc[uu][vv][co]: v2f lanes = (kh=0 partial, kh=1 partial) ... actually
    // lanes = (kw-even partial, kw-odd partial); summed at the end.
    v2f acc[2][2][kCout];
    #pragma unroll
    for (int co = 0; co < kCout; ++co) {
        const float bb = bias[co];
        #pragma unroll
        for (int uu = 0; uu < 2; ++uu)
            #pragma unroll
            for (int vv = 0; vv < 2; ++vv)
                acc[uu][vv][co] = (v2f){bb, 0.f};
    }

    const float* xb = x + (size_t)b * kCin * kCiStride + toff;

    #pragma unroll
    for (int e1 = 0; e1 < 4; ++e1) {
        const int d1 = u0 + e1 - 1;
        if (d1 < 0 || d1 >= kD1) continue;             // wave-uniform
        #pragma unroll
        for (int e2 = 0; e2 < 4; ++e2) {
            const int d2 = v0 + e2 - 1;
            if (d2 < 0 || d2 >= kD2) continue;         // wave-uniform
            const float* sp0 = xb + (size_t)(d1 * kD2 + d2) * kSlice;
            #pragma unroll
            for (int ci = 0; ci < kCin; ++ci) {
                const float* sp = sp0 + (size_t)ci * kCiStride;
                const v2f r0 = *reinterpret_cast<const v2f*>(sp);        // row 2ho
                const v2f r1 = *reinterpret_cast<const v2f*>(sp + kW);   // row 2ho+1
                #pragma unroll
                for (int uu = 0; uu < 2; ++uu) {
                    const int ku = e1 - uu;
                    if (ku < 0 || ku > 2) continue;    // compile-time
                    #pragma unroll
                    for (int vv = 0; vv < 2; ++vv) {
                        const int kv = e2 - vv;
                        if (kv < 0 || kv > 2) continue;  // compile-time
                        #pragma unroll
                        for (int co = 0; co < kCout; ++co) {
                            const float* wp = w + (((co * kCin + ci) * 3 + ku) * 3 + kv) * 4;
                            const v2f w01 = {wp[0], wp[1]};   // kh=0, kw=0..1
                            const v2f w23 = {wp[2], wp[3]};   // kh=1, kw=0..1
                            acc[uu][vv][co] =
                                __builtin_elementwise_fma(r0, w01, acc[uu][vv][co]);
                            acc[uu][vv][co] =
                                __builtin_elementwise_fma(r1, w23, acc[uu][vv][co]);
                        }
                    }
                }
            }
        }
    }

    #pragma unroll
    for (int co = 0; co < kCout; ++co)
        #pragma unroll
        for (int uu = 0; uu < 2; ++uu)
            #pragma unroll
            for (int vv = 0; vv < 2; ++vv) {
                float* yp = y
                    + ((((size_t)(b * kCout + co) * kD1 + (u0 + uu)) * kD2 + (v0 + vv)) * kHO + ho) * kWO
                    + wo;
                *yp = acc[uu][vv][co].x + acc[uu][vv][co].y;
            }
}

}  // namespace

extern "C" void kernel_launch(void* const* d_in, const int* in_sizes, int n_in,
                              void* d_out, int out_size, void* d_ws, size_t ws_size,
                              hipStream_t stream) {
    const float* x    = (const float*)d_in[0];
    const float* w    = (const float*)d_in[1];
    const float* bias = (const float*)d_in[2];
    float* y          = (float*)d_out;

    dim3 block(32, 8, 1);                  // (wo, h-row)
    dim3 grid(kB * 2 * 2 * 16 * 16, 1, 1); // 4096 blocks, decoded in-kernel
    hipLaunchKernelGGL(conv4d_strang, grid, block, 0, stream, x, w, bias, y);
}